// Round 2
// baseline (802.539 us; speedup 1.0000x reference)
//
#include <hip/hip_runtime.h>
#include <hip/hip_bf16.h>
#include <cmath>

using bf16 = __hip_bfloat16;
using bf16x8_t = __attribute__((ext_vector_type(8))) short;
using f32x4_t  = __attribute__((ext_vector_type(4))) float;

constexpr int kT = 8;
constexpr int kDIM = 768, kNH = 8, kHD = 96;
constexpr int kN = 1570;                        // 8*14*14 + 1 + 1
constexpr int kB = 4;
constexpr int kM = kB * kN;                     // 6280
constexpr int kBNH = kB * kNH;                  // 32
constexpr long kPoolRows  = (long)kBNH * kN;    // 50240
constexpr long kPoolElems = kPoolRows * kHD;    // 4,823,040

// ---------------- dtype probe + input conversion ----------------------------
struct SegTab { const void* src[22]; long cnt[22]; };

__global__ void detect_kernel(const unsigned* __restrict__ probe,
                              unsigned* __restrict__ flag) {
  // norm1_g is all-ones: bf16-pair word = 0x3F803F80, fp32 word = 0x3F800000
  *flag = (probe[0] == 0x3F803F80u) ? 1u : 0u;
}

__global__ void convert_kernel(SegTab tab, bf16* __restrict__ cin,
                               const unsigned* __restrict__ flag, long total) {
  const bool isb = (*flag != 0u);
  const long stride = (long)gridDim.x * blockDim.x;
  for (long i = (long)blockIdx.x * blockDim.x + threadIdx.x; i < total; i += stride) {
    long base = 0, loc = i; int s = 0;
    for (int k = 0; k < 22; ++k) {
      if (i < base + tab.cnt[k]) { s = k; loc = i - base; break; }
      base += tab.cnt[k];
    }
    if (isb) ((unsigned short*)cin)[i] = ((const unsigned short*)tab.src[s])[loc];
    else     cin[i] = (bf16)(((const float*)tab.src[s])[loc]);
  }
}

__device__ __forceinline__ void gload_lds16(const bf16* g, bf16* l) {
  __builtin_amdgcn_global_load_lds(
      (const __attribute__((address_space(1))) unsigned int*)g,
      (__attribute__((address_space(3))) unsigned int*)l, 16, 0, 0);
}

// ---------------- GEMM: C[M,Nout] = A[M,K] @ W[Nout,K]^T + bias, epilogues ---
// EPI 0: +bias ; EPI 1: +bias then exact GELU ; EPI 2: +bias + residual
// DUAL: choose bf16 vs f32 output by *flagp
template<int EPI, int DUAL>
__launch_bounds__(256, 2)
__global__ void gemm_bt(const bf16* __restrict__ A, const bf16* __restrict__ Wt,
                        const bf16* __restrict__ bias, const bf16* __restrict__ res,
                        bf16* __restrict__ C, float* __restrict__ Cf,
                        const unsigned* __restrict__ flagp,
                        int M, int K, int Nout)
{
  __shared__ bf16 As[128 * 32];
  __shared__ bf16 Bs[128 * 32];
  const int tid  = threadIdx.x;
  const int lane = tid & 63;
  const int wv   = tid >> 6;
  const int wr   = wv >> 1, wc = wv & 1;
  const long tile_m = (long)blockIdx.x * 128;
  const long tile_n = (long)blockIdx.y * 128;

  bool isb = true;
  if constexpr (DUAL) isb = (*flagp != 0u);

  f32x4_t zero = {0.f, 0.f, 0.f, 0.f};
  f32x4_t acc[4][4];
#pragma unroll
  for (int i = 0; i < 4; ++i)
#pragma unroll
    for (int j = 0; j < 4; ++j) acc[i][j] = zero;

  const int r0 = (tid * 8) >> 5;
  const int c0 = (tid * 8) & 31;
  long ar0 = tile_m + r0;      if (ar0 > M - 1) ar0 = M - 1;
  long ar1 = tile_m + r0 + 64; if (ar1 > M - 1) ar1 = M - 1;
  const bf16* Ag0 = A  + ar0 * K + c0;
  const bf16* Ag1 = A  + ar1 * K + c0;
  const bf16* Bg0 = Wt + (tile_n + r0) * K + c0;
  const bf16* Bg1 = Wt + (tile_n + r0 + 64) * K + c0;
  bf16* Asl0 = As + wv * 512;
  bf16* Asl1 = As + 2048 + wv * 512;
  bf16* Bsl0 = Bs + wv * 512;
  bf16* Bsl1 = Bs + 2048 + wv * 512;

  const int kgrp = (lane >> 4) * 8;
  const int rA = wr * 64 + (lane & 15);
  const int rB = wc * 64 + (lane & 15);

  const int ksteps = K >> 5;
  for (int kt = 0; kt < ksteps; ++kt) {
    const int k0 = kt << 5;
    gload_lds16(Ag0 + k0, Asl0);
    gload_lds16(Ag1 + k0, Asl1);
    gload_lds16(Bg0 + k0, Bsl0);
    gload_lds16(Bg1 + k0, Bsl1);
    __syncthreads();                 // drains vmcnt(0) before barrier
    bf16x8_t a[4], b[4];
#pragma unroll
    for (int m = 0; m < 4; ++m)
      a[m] = *(const bf16x8_t*)&As[(rA + m * 16) * 32 + kgrp];
#pragma unroll
    for (int n = 0; n < 4; ++n)
      b[n] = *(const bf16x8_t*)&Bs[(rB + n * 16) * 32 + kgrp];
#pragma unroll
    for (int m = 0; m < 4; ++m)
#pragma unroll
      for (int n = 0; n < 4; ++n)
        acc[m][n] = __builtin_amdgcn_mfma_f32_16x16x32_bf16(a[m], b[n], acc[m][n], 0, 0, 0);
    __syncthreads();
  }

  const long colBase = tile_n + wc * 64 + (lane & 15);
  const long rowBase = tile_m + wr * 64 + ((lane >> 4) << 2);
#pragma unroll
  for (int n = 0; n < 4; ++n) {
    const long col = colBase + n * 16;
    const float bv = (float)bias[col];
#pragma unroll
    for (int m = 0; m < 4; ++m) {
      const long row0 = rowBase + m * 16;
#pragma unroll
      for (int r = 0; r < 4; ++r) {
        const long row = row0 + r;
        if (row < M) {
          float v2 = acc[m][n][r] + bv;
          if constexpr (EPI == 1) {
            v2 = 0.5f * v2 * (1.f + erff(v2 * 0.70710678118654752f));
          } else if constexpr (EPI == 2) {
            v2 += (float)res[row * Nout + col];
          }
          if constexpr (DUAL) {
            if (isb) C[row * Nout + col] = (bf16)v2;
            else     Cf[row * Nout + col] = v2;
          } else {
            C[row * Nout + col] = (bf16)v2;
          }
        }
      }
    }
  }
}

// ---------------- LayerNorm over DIM=768, one block per row -----------------
__global__ void ln768_kernel(const bf16* __restrict__ x, const bf16* __restrict__ g,
                             const bf16* __restrict__ bta, bf16* __restrict__ y)
{
  const long row = blockIdx.x;
  const int tid = threadIdx.x;
  const bf16* xr = x + row * kDIM;
  float v[3];
  float s = 0.f, ss = 0.f;
#pragma unroll
  for (int i = 0; i < 3; ++i) {
    v[i] = (float)xr[tid + i * 256];
    s += v[i]; ss += v[i] * v[i];
  }
#pragma unroll
  for (int off = 32; off; off >>= 1) {
    s  += __shfl_xor(s, off);
    ss += __shfl_xor(ss, off);
  }
  __shared__ float red[8];
  const int wv = tid >> 6;
  if ((tid & 63) == 0) { red[wv] = s; red[4 + wv] = ss; }
  __syncthreads();
  s  = red[0] + red[1] + red[2] + red[3];
  ss = red[4] + red[5] + red[6] + red[7];
  const float mean = s * (1.f / kDIM);
  const float var  = ss * (1.f / kDIM) - mean * mean;
  const float rstd = rsqrtf(var + 1e-5f);
  bf16* yr = y + row * kDIM;
#pragma unroll
  for (int i = 0; i < 3; ++i) {
    const int c = tid + i * 256;
    yr[c] = (bf16)((v[i] - mean) * rstd * (float)g[c] + (float)bta[c]);
  }
}

// ---------------- depthwise 3x3x3 conv pooling (q,k,v) ----------------------
__global__ void convpool_kernel(const bf16* __restrict__ qkv,
                                const bf16* __restrict__ cwq,
                                const bf16* __restrict__ cwk,
                                const bf16* __restrict__ cwv,
                                bf16* __restrict__ pool)
{
  const int s  = blockIdx.z;
  const int bh = blockIdx.y;
  const int t  = blockIdx.x;
  const int d  = threadIdx.x;   // 0..95
  const bf16* cw = (s == 0) ? cwq : (s == 1) ? cwk : cwv;
  float wgt[27];
#pragma unroll
  for (int i = 0; i < 27; ++i) wgt[i] = (float)cw[d * 27 + i];
  const int b = bh >> 3, h = bh & 7;
  const bf16* in0 = qkv + (long)b * kN * 2304 + s * kDIM + h * kHD + d;
  bf16* out0 = pool + (long)s * kPoolElems + (long)bh * kN * kHD + d;
  for (int p = threadIdx.y; p < 196; p += 2) {
    const int y = p / 14, x0 = p % 14;
    float acc = 0.f;
#pragma unroll
    for (int dt = 0; dt < 3; ++dt) {
      const int tt = t + dt - 1;
      if ((unsigned)tt < (unsigned)kT) {
#pragma unroll
        for (int dy = 0; dy < 3; ++dy) {
          const int yy = y + dy - 1;
          if ((unsigned)yy < 14u) {
#pragma unroll
            for (int dx = 0; dx < 3; ++dx) {
              const int xx = x0 + dx - 1;
              if ((unsigned)xx < 14u) {
                const int n = 2 + (tt * 14 + yy) * 14 + xx;
                acc += (float)in0[(long)n * 2304] * wgt[dt * 9 + dy * 3 + dx];
              }
            }
          }
        }
      }
    }
    const int n = 2 + (t * 14 + y) * 14 + x0;
    out0[(long)n * kHD] = (bf16)acc;
  }
  if (t == 0 && threadIdx.y == 0) {
    out0[0]   = in0[0];        // glob token passthrough
    out0[kHD] = in0[2304];     // cls token passthrough
  }
}

// ---------------- LayerNorm over HD=96, one wave per row, in place ----------
__global__ void ln96_kernel(bf16* __restrict__ pool,
                            const bf16* __restrict__ gq, const bf16* __restrict__ bq,
                            const bf16* __restrict__ gk, const bf16* __restrict__ bk,
                            const bf16* __restrict__ gv, const bf16* __restrict__ bv)
{
  const int z = blockIdx.y;
  bf16* buf = pool + (long)z * kPoolElems;
  const bf16* g  = (z == 0) ? gq : (z == 1) ? gk : gv;
  const bf16* be = (z == 0) ? bq : (z == 1) ? bk : bv;
  const long row = (long)blockIdx.x * 4 + (threadIdx.x >> 6);
  if (row >= kPoolRows) return;
  const int lane = threadIdx.x & 63;
  bf16* p = buf + row * kHD;
  float a0 = 0.f, a1 = 0.f;
  if (lane < 48) {
    a0 = (float)p[lane * 2];
    a1 = (float)p[lane * 2 + 1];
  }
  float sSum = a0 + a1, sSq = a0 * a0 + a1 * a1;
#pragma unroll
  for (int off = 32; off; off >>= 1) {
    sSum += __shfl_xor(sSum, off);
    sSq  += __shfl_xor(sSq, off);
  }
  const float mean = sSum * (1.f / 96);
  const float var  = sSq * (1.f / 96) - mean * mean;
  const float rstd = rsqrtf(var + 1e-5f);
  if (lane < 48) {
    p[lane * 2]     = (bf16)((a0 - mean) * rstd * (float)g[lane * 2]     + (float)be[lane * 2]);
    p[lane * 2 + 1] = (bf16)((a1 - mean) * rstd * (float)g[lane * 2 + 1] + (float)be[lane * 2 + 1]);
  }
}

// ---------------- sparse masked attention: row i attends to {0, i} ----------
__global__ void attn_kernel(const bf16* __restrict__ pool, bf16* __restrict__ o)
{
  const long idx = (long)blockIdx.x * 4 + (threadIdx.x >> 6);
  if (idx >= kPoolRows) return;
  const int bh = (int)(idx / kN);
  const int i  = (int)(idx - (long)bh * kN);
  const int lane = threadIdx.x & 63;
  const bf16* qrow  = pool + ((long)bh * kN + i) * kHD;
  const bf16* kbase = pool + kPoolElems + (long)bh * kN * kHD;
  const bf16* vbase = pool + 2 * kPoolElems + (long)bh * kN * kHD;
  float q0 = 0, q1 = 0, ki0 = 0, ki1 = 0, k00 = 0, k01 = 0;
  float vi0 = 0, vi1 = 0, v00 = 0, v01 = 0;
  if (lane < 48) {
    const int c = lane * 2;
    q0  = (float)qrow[c];                  q1  = (float)qrow[c + 1];
    ki0 = (float)kbase[(long)i * kHD + c]; ki1 = (float)kbase[(long)i * kHD + c + 1];
    k00 = (float)kbase[c];                 k01 = (float)kbase[c + 1];
    vi0 = (float)vbase[(long)i * kHD + c]; vi1 = (float)vbase[(long)i * kHD + c + 1];
    v00 = (float)vbase[c];                 v01 = (float)vbase[c + 1];
  }
  float ds = q0 * ki0 + q1 * ki1;
  float dg = q0 * k00 + q1 * k01;
#pragma unroll
  for (int off = 32; off; off >>= 1) {
    ds += __shfl_xor(ds, off);
    dg += __shfl_xor(dg, off);
  }
  float o0, o1;
  if (i == 0) { o0 = v00; o1 = v01; }
  else {
    const float scale = 0.10206207261596575f; // 96^-0.5
    const float l0 = dg * scale, li = ds * scale;
    const float mx = fmaxf(l0, li);
    const float e0 = __expf(l0 - mx), ei = __expf(li - mx);
    const float inv = 1.f / (e0 + ei);
    o0 = (e0 * v00 + ei * vi0) * inv;
    o1 = (e0 * v01 + ei * vi1) * inv;
  }
  if (lane < 48) {
    const int b = bh >> 3, h = bh & 7;
    bf16* orow = o + ((long)b * kN + i) * kDIM + h * kHD + lane * 2;
    orow[0] = (bf16)o0;
    orow[1] = (bf16)o1;
  }
}

extern "C" void kernel_launch(void* const* d_in, const int* in_sizes, int n_in,
                              void* d_out, int out_size, void* d_ws, size_t ws_size,
                              hipStream_t stream)
{
  // indices of the 22 float tensors in setup_inputs order (skip t,h,w scalars)
  const int map[22] = {0,4,5,6,7,8,9,10,11,12,13,14,15,16,17,18,19,20,21,22,23,24};

  char* ws = (char*)d_ws;
  unsigned* flag = (unsigned*)ws;

  size_t off = 256;
  auto take = [&](size_t bytes) {
    size_t r = off;
    off += (bytes + 255) & ~(size_t)255;
    return r;
  };

  SegTab tab;
  long total = 0;
  for (int j = 0; j < 22; ++j) { tab.src[j] = d_in[map[j]]; tab.cnt[j] = in_sizes[map[j]]; }

  size_t cin_off = take(2 * (size_t)(in_sizes[0] + 1) * 4);  // placeholder recomputed below
  // recompute precisely: total elements
  for (int j = 0; j < 22; ++j) total += in_sizes[map[j]];
  off = 256;
  cin_off = take((size_t)total * 2);
  bf16* cin = (bf16*)(ws + cin_off);

  // named converted pointers (packed in map order)
  bf16* cp[22];
  { long acc = 0;
    for (int j = 0; j < 22; ++j) { cp[j] = cin + acc; acc += tab.cnt[j]; } }
  bf16* x_c    = cp[0];
  bf16* n1g_c  = cp[1],  *n1b_c = cp[2];
  bf16* qkvw_c = cp[3],  *qkvb_c = cp[4];
  bf16* cwq_c  = cp[5],  *nqg_c = cp[6],  *nqb_c = cp[7];
  bf16* cwk_c  = cp[8],  *nkg_c = cp[9],  *nkb_c = cp[10];
  bf16* cwv_c  = cp[11], *nvg_c = cp[12], *nvb_c = cp[13];
  bf16* projw_c = cp[14], *projb_c = cp[15];
  bf16* n2g_c  = cp[16], *n2b_c = cp[17];
  bf16* fc1w_c = cp[18], *fc1b_c = cp[19];
  bf16* fc2w_c = cp[20], *fc2b_c = cp[21];

  bf16* qkv  = (bf16*)(ws + take(38584320));  // also h1 (M x 3072)
  bf16* xn   = (bf16*)(ws + take(9646080));   // also o
  bf16* pool = (bf16*)(ws + take(28938240));  // also x2n
  bf16* x1   = (bf16*)(ws + take(9646080));
  bf16* o   = xn;
  bf16* h1  = qkv;
  bf16* x2n = pool;

  bf16*  out_b = (bf16*)d_out;
  float* out_f = (float*)d_out;

  detect_kernel<<<1, 1, 0, stream>>>((const unsigned*)d_in[4], flag);
  convert_kernel<<<2048, 256, 0, stream>>>(tab, cin, flag, total);

  ln768_kernel<<<kM, 256, 0, stream>>>(x_c, n1g_c, n1b_c, xn);
  gemm_bt<0,0><<<dim3(50, 18), 256, 0, stream>>>(xn, qkvw_c, qkvb_c, nullptr, qkv, nullptr, nullptr, kM, 768, 2304);
  convpool_kernel<<<dim3(kT, kBNH, 3), dim3(96, 2), 0, stream>>>(qkv, cwq_c, cwk_c, cwv_c, pool);
  ln96_kernel<<<dim3((int)((kPoolRows + 3) / 4), 3), 256, 0, stream>>>(pool, nqg_c, nqb_c, nkg_c, nkb_c, nvg_c, nvb_c);
  attn_kernel<<<(int)((kPoolRows + 3) / 4), 256, 0, stream>>>(pool, o);
  gemm_bt<2,0><<<dim3(50, 6), 256, 0, stream>>>(o, projw_c, projb_c, x_c, x1, nullptr, nullptr, kM, 768, 768);
  ln768_kernel<<<kM, 256, 0, stream>>>(x1, n2g_c, n2b_c, x2n);
  gemm_bt<1,0><<<dim3(50, 24), 256, 0, stream>>>(x2n, fc1w_c, fc1b_c, nullptr, h1, nullptr, nullptr, kM, 768, 3072);
  gemm_bt<2,1><<<dim3(50, 6), 256, 0, stream>>>(h1, fc2w_c, fc2b_c, x1, out_b, out_f, flag, kM, 3072, 768);
}

// Round 3
// 350.162 us; speedup vs baseline: 2.2919x; 2.2919x over previous
//
#include <hip/hip_runtime.h>
#include <hip/hip_bf16.h>
#include <cmath>

using bf16 = __hip_bfloat16;
using bf16x8_t = __attribute__((ext_vector_type(8))) short;
using f32x4_t  = __attribute__((ext_vector_type(4))) float;

constexpr int kT = 8;
constexpr int kDIM = 768, kNH = 8, kHD = 96;
constexpr int kN = 1570;                        // 8*14*14 + 1 + 1
constexpr int kB = 4;
constexpr int kM = kB * kN;                     // 6280
constexpr int kBNH = kB * kNH;                  // 32
constexpr long kPoolRows  = (long)kBNH * kN;    // 50240
constexpr long kPoolElems = kPoolRows * kHD;    // 4,823,040

// ---------------- dtype probe + input conversion ----------------------------
struct SegTab { const void* src[22]; long start[23]; };

__global__ void detect_kernel(const unsigned* __restrict__ probe,
                              unsigned* __restrict__ flag) {
  // norm1_g is all-ones: bf16-pair word = 0x3F803F80, fp32 word = 0x3F800000
  *flag = (probe[0] == 0x3F803F80u) ? 1u : 0u;
}

__global__ void convert_kernel(SegTab tab, bf16* __restrict__ cin,
                               const unsigned* __restrict__ flag, long chunks) {
  const bool isb = (*flag != 0u);
  const long stride = (long)gridDim.x * blockDim.x;
  for (long c = (long)blockIdx.x * blockDim.x + threadIdx.x; c < chunks; c += stride) {
    const long e8 = c * 8;
    int lo = 0, hi = 22;
    while (hi - lo > 1) { int mid = (lo + hi) >> 1; if (e8 >= tab.start[mid]) lo = mid; else hi = mid; }
    const long e = e8 - tab.start[lo];
    if (isb) {
      *(bf16x8_t*)(cin + e8) = *(const bf16x8_t*)((const unsigned short*)tab.src[lo] + e);
    } else {
      const float* s = (const float*)tab.src[lo] + e;
      float4 a = *(const float4*)s;
      float4 b = *(const float4*)(s + 4);
      bf16 r[8];
      r[0] = (bf16)a.x; r[1] = (bf16)a.y; r[2] = (bf16)a.z; r[3] = (bf16)a.w;
      r[4] = (bf16)b.x; r[5] = (bf16)b.y; r[6] = (bf16)b.z; r[7] = (bf16)b.w;
      *(bf16x8_t*)(cin + e8) = *(bf16x8_t*)r;
    }
  }
}

__device__ __forceinline__ void gload_lds16(const bf16* g, bf16* l) {
  __builtin_amdgcn_global_load_lds(
      (const __attribute__((address_space(1))) unsigned int*)g,
      (__attribute__((address_space(3))) unsigned int*)l, 16, 0, 0);
}

// ---------------- GEMM: C[M,Nout] = A[M,K] @ W[Nout,K]^T + bias, epilogues ---
// EPI 0: +bias ; EPI 1: +bias then exact GELU ; EPI 2: +bias + residual
// DUAL: choose bf16 vs f32 output by *flagp
template<int EPI, int DUAL>
__launch_bounds__(256, 2)
__global__ void gemm_bt(const bf16* __restrict__ A, const bf16* __restrict__ Wt,
                        const bf16* __restrict__ bias, const bf16* __restrict__ res,
                        bf16* __restrict__ C, float* __restrict__ Cf,
                        const unsigned* __restrict__ flagp,
                        int M, int K, int Nout)
{
  __shared__ bf16 As[128 * 32];
  __shared__ bf16 Bs[128 * 32];
  const int tid  = threadIdx.x;
  const int lane = tid & 63;
  const int wv   = tid >> 6;
  const int wr   = wv >> 1, wc = wv & 1;
  const long tile_m = (long)blockIdx.x * 128;
  const long tile_n = (long)blockIdx.y * 128;

  bool isb = true;
  if constexpr (DUAL) isb = (*flagp != 0u);

  f32x4_t zero = {0.f, 0.f, 0.f, 0.f};
  f32x4_t acc[4][4];
#pragma unroll
  for (int i = 0; i < 4; ++i)
#pragma unroll
    for (int j = 0; j < 4; ++j) acc[i][j] = zero;

  const int r0 = (tid * 8) >> 5;
  const int c0 = (tid * 8) & 31;
  long ar0 = tile_m + r0;      if (ar0 > M - 1) ar0 = M - 1;
  long ar1 = tile_m + r0 + 64; if (ar1 > M - 1) ar1 = M - 1;
  const bf16* Ag0 = A  + ar0 * K + c0;
  const bf16* Ag1 = A  + ar1 * K + c0;
  const bf16* Bg0 = Wt + (tile_n + r0) * K + c0;
  const bf16* Bg1 = Wt + (tile_n + r0 + 64) * K + c0;
  bf16* Asl0 = As + wv * 512;
  bf16* Asl1 = As + 2048 + wv * 512;
  bf16* Bsl0 = Bs + wv * 512;
  bf16* Bsl1 = Bs + 2048 + wv * 512;

  const int kgrp = (lane >> 4) * 8;
  const int rA = wr * 64 + (lane & 15);
  const int rB = wc * 64 + (lane & 15);

  const int ksteps = K >> 5;
  for (int kt = 0; kt < ksteps; ++kt) {
    const int k0 = kt << 5;
    gload_lds16(Ag0 + k0, Asl0);
    gload_lds16(Ag1 + k0, Asl1);
    gload_lds16(Bg0 + k0, Bsl0);
    gload_lds16(Bg1 + k0, Bsl1);
    __syncthreads();                 // drains vmcnt(0) before barrier
    bf16x8_t a[4], b[4];
#pragma unroll
    for (int m = 0; m < 4; ++m)
      a[m] = *(const bf16x8_t*)&As[(rA + m * 16) * 32 + kgrp];
#pragma unroll
    for (int n = 0; n < 4; ++n)
      b[n] = *(const bf16x8_t*)&Bs[(rB + n * 16) * 32 + kgrp];
#pragma unroll
    for (int m = 0; m < 4; ++m)
#pragma unroll
      for (int n = 0; n < 4; ++n)
        acc[m][n] = __builtin_amdgcn_mfma_f32_16x16x32_bf16(a[m], b[n], acc[m][n], 0, 0, 0);
    __syncthreads();
  }

  const long colBase = tile_n + wc * 64 + (lane & 15);
  const long rowBase = tile_m + wr * 64 + ((lane >> 4) << 2);
#pragma unroll
  for (int n = 0; n < 4; ++n) {
    const long col = colBase + n * 16;
    const float bv = (float)bias[col];
#pragma unroll
    for (int m = 0; m < 4; ++m) {
      const long row0 = rowBase + m * 16;
#pragma unroll
      for (int r = 0; r < 4; ++r) {
        const long row = row0 + r;
        if (row < M) {
          float v2 = acc[m][n][r] + bv;
          if constexpr (EPI == 1) {
            v2 = 0.5f * v2 * (1.f + erff(v2 * 0.70710678118654752f));
          } else if constexpr (EPI == 2) {
            v2 += (float)res[row * Nout + col];
          }
          if constexpr (DUAL) {
            if (isb) C[row * Nout + col] = (bf16)v2;
            else     Cf[row * Nout + col] = v2;
          } else {
            C[row * Nout + col] = (bf16)v2;
          }
        }
      }
    }
  }
}

// ---------------- LayerNorm over DIM=768, one block per row -----------------
__global__ void ln768_kernel(const bf16* __restrict__ x, const bf16* __restrict__ g,
                             const bf16* __restrict__ bta, bf16* __restrict__ y)
{
  const long row = blockIdx.x;
  const int tid = threadIdx.x;
  const bf16* xr = x + row * kDIM;
  float v[3];
  float s = 0.f, ss = 0.f;
#pragma unroll
  for (int i = 0; i < 3; ++i) {
    v[i] = (float)xr[tid + i * 256];
    s += v[i]; ss += v[i] * v[i];
  }
#pragma unroll
  for (int off = 32; off; off >>= 1) {
    s  += __shfl_xor(s, off);
    ss += __shfl_xor(ss, off);
  }
  __shared__ float red[8];
  const int wv = tid >> 6;
  if ((tid & 63) == 0) { red[wv] = s; red[4 + wv] = ss; }
  __syncthreads();
  s  = red[0] + red[1] + red[2] + red[3];
  ss = red[4] + red[5] + red[6] + red[7];
  const float mean = s * (1.f / kDIM);
  const float var  = ss * (1.f / kDIM) - mean * mean;
  const float rstd = rsqrtf(var + 1e-5f);
  bf16* yr = y + row * kDIM;
#pragma unroll
  for (int i = 0; i < 3; ++i) {
    const int c = tid + i * 256;
    yr[c] = (bf16)((v[i] - mean) * rstd * (float)g[c] + (float)bta[c]);
  }
}

// ---------------- depthwise 3x3x3 conv pooling, LDS-staged v2 ---------------
// grid (kT, kBNH, 9): z = s*3 + cgrp (32 channels per block). block 256.
// LDS tile: [slice 0..2][ty 0..15][tx 0..15][ch-stride 40] bf16 = 61,440 B.
// Zero-padded spatially -> no bounds checks in the 27-tap loop; taps become
// 27 independent ds_read_b32 with compile-time offsets.
__launch_bounds__(256, 2)
__global__ void convpool2_kernel(const bf16* __restrict__ qkv,
                                 const bf16* __restrict__ cwq,
                                 const bf16* __restrict__ cwk,
                                 const bf16* __restrict__ cwv,
                                 bf16* __restrict__ pool)
{
  __shared__ bf16 tile[3 * 256 * 40];   // 61,440 B
  const int t    = blockIdx.x;
  const int bh   = blockIdx.y;
  const int z    = blockIdx.z;
  const int s    = z / 3, cgrp = z - s * 3;
  const int tid  = threadIdx.x;
  const int b    = bh >> 3, h = bh & 7;

  const bf16* src0 = qkv + (long)(b * kN) * 2304 + s * kDIM + h * kHD + cgrp * 32;

  {
    f32x4_t z4 = {0.f, 0.f, 0.f, 0.f};
    for (int i = tid; i < 3840; i += 256)
      *(f32x4_t*)((char*)tile + (long)i * 16) = z4;
  }
  __syncthreads();

  // stage: 3 slices x 196 px x 4 chunks of 8 ch
  for (int c = tid; c < 2352; c += 256) {
    const int slice = c / 784;
    const int rem   = c - slice * 784;
    const int p     = rem >> 2;
    const int seg   = rem & 3;
    const int tt    = t + slice - 1;
    if ((unsigned)tt < 8u) {
      const int y = p / 14, x = p - y * 14;
      const int n = 2 + tt * 196 + p;
      const bf16x8_t v = *(const bf16x8_t*)(src0 + (long)n * 2304 + seg * 8);
      *(bf16x8_t*)((char*)tile + ((long)(slice * 256 + (y + 1) * 16 + (x + 1)) * 40 + seg * 8) * 2) = v;
    }
  }

  // per-thread weights (2 channels)
  const int dpair = tid & 15;
  const int pg    = tid >> 4;
  const int d0    = cgrp * 32 + dpair * 2;
  const bf16* cw  = (s == 0) ? cwq : (s == 1) ? cwk : cwv;
  float w0[27], w1[27];
#pragma unroll
  for (int i = 0; i < 27; ++i) {
    w0[i] = (float)cw[d0 * 27 + i];
    w1[i] = (float)cw[(d0 + 1) * 27 + i];
  }
  __syncthreads();

  bf16* out0 = pool + (long)s * kPoolElems + (long)bh * kN * kHD;
  for (int p = pg; p < 196; p += 16) {
    const int y = p / 14, x = p - y * 14;
    const char* bp = (const char*)tile + ((long)(y * 16 + x) * 40 + dpair * 2) * 2;
    float a0 = 0.f, a1 = 0.f;
#pragma unroll
    for (int dt = 0; dt < 3; ++dt)
#pragma unroll
      for (int dy = 0; dy < 3; ++dy)
#pragma unroll
        for (int dx = 0; dx < 3; ++dx) {
          const unsigned u = *(const unsigned*)(bp + dt * 20480 + dy * 1280 + dx * 80);
          const int i = (dt * 3 + dy) * 3 + dx;
          a0 = fmaf(__uint_as_float(u << 16), w0[i], a0);
          a1 = fmaf(__uint_as_float(u & 0xffff0000u), w1[i], a1);
        }
    const int n = 2 + t * 196 + p;
    bf16 r0 = (bf16)a0, r1 = (bf16)a1;
    unsigned pk = ((unsigned)*(unsigned short*)&r1 << 16) | *(unsigned short*)&r0;
    *(unsigned*)((char*)(out0 + (long)n * kHD + d0)) = pk;
  }
  // glob + cls passthrough (32 channels of this block)
  if (t == 0 && tid < 64) {
    const int tok = tid >> 5, dd = tid & 31;
    out0[(long)tok * kHD + cgrp * 32 + dd] = src0[(long)tok * 2304 + dd];
  }
}

// ---------------- LayerNorm over HD=96, one wave per row, in place ----------
__global__ void ln96_kernel(bf16* __restrict__ pool,
                            const bf16* __restrict__ gq, const bf16* __restrict__ bq,
                            const bf16* __restrict__ gk, const bf16* __restrict__ bk,
                            const bf16* __restrict__ gv, const bf16* __restrict__ bv)
{
  const int z = blockIdx.y;
  bf16* buf = pool + (long)z * kPoolElems;
  const bf16* g  = (z == 0) ? gq : (z == 1) ? gk : gv;
  const bf16* be = (z == 0) ? bq : (z == 1) ? bk : bv;
  const long row = (long)blockIdx.x * 4 + (threadIdx.x >> 6);
  if (row >= kPoolRows) return;
  const int lane = threadIdx.x & 63;
  bf16* p = buf + row * kHD;
  float a0 = 0.f, a1 = 0.f;
  if (lane < 48) {
    a0 = (float)p[lane * 2];
    a1 = (float)p[lane * 2 + 1];
  }
  float sSum = a0 + a1, sSq = a0 * a0 + a1 * a1;
#pragma unroll
  for (int off = 32; off; off >>= 1) {
    sSum += __shfl_xor(sSum, off);
    sSq  += __shfl_xor(sSq, off);
  }
  const float mean = sSum * (1.f / 96);
  const float var  = sSq * (1.f / 96) - mean * mean;
  const float rstd = rsqrtf(var + 1e-5f);
  if (lane < 48) {
    p[lane * 2]     = (bf16)((a0 - mean) * rstd * (float)g[lane * 2]     + (float)be[lane * 2]);
    p[lane * 2 + 1] = (bf16)((a1 - mean) * rstd * (float)g[lane * 2 + 1] + (float)be[lane * 2 + 1]);
  }
}

// ---------------- sparse masked attention: row i attends to {0, i} ----------
__global__ void attn_kernel(const bf16* __restrict__ pool, bf16* __restrict__ o)
{
  const long idx = (long)blockIdx.x * 4 + (threadIdx.x >> 6);
  if (idx >= kPoolRows) return;
  const int bh = (int)(idx / kN);
  const int i  = (int)(idx - (long)bh * kN);
  const int lane = threadIdx.x & 63;
  const bf16* qrow  = pool + ((long)bh * kN + i) * kHD;
  const bf16* kbase = pool + kPoolElems + (long)bh * kN * kHD;
  const bf16* vbase = pool + 2 * kPoolElems + (long)bh * kN * kHD;
  float q0 = 0, q1 = 0, ki0 = 0, ki1 = 0, k00 = 0, k01 = 0;
  float vi0 = 0, vi1 = 0, v00 = 0, v01 = 0;
  if (lane < 48) {
    const int c = lane * 2;
    q0  = (float)qrow[c];                  q1  = (float)qrow[c + 1];
    ki0 = (float)kbase[(long)i * kHD + c]; ki1 = (float)kbase[(long)i * kHD + c + 1];
    k00 = (float)kbase[c];                 k01 = (float)kbase[c + 1];
    vi0 = (float)vbase[(long)i * kHD + c]; vi1 = (float)vbase[(long)i * kHD + c + 1];
    v00 = (float)vbase[c];                 v01 = (float)vbase[c + 1];
  }
  float ds = q0 * ki0 + q1 * ki1;
  float dg = q0 * k00 + q1 * k01;
#pragma unroll
  for (int off = 32; off; off >>= 1) {
    ds += __shfl_xor(ds, off);
    dg += __shfl_xor(dg, off);
  }
  float o0, o1;
  if (i == 0) { o0 = v00; o1 = v01; }
  else {
    const float scale = 0.10206207261596575f; // 96^-0.5
    const float l0 = dg * scale, li = ds * scale;
    const float mx = fmaxf(l0, li);
    const float e0 = __expf(l0 - mx), ei = __expf(li - mx);
    const float inv = 1.f / (e0 + ei);
    o0 = (e0 * v00 + ei * vi0) * inv;
    o1 = (e0 * v01 + ei * vi1) * inv;
  }
  if (lane < 48) {
    const int b = bh >> 3, h = bh & 7;
    bf16* orow = o + ((long)b * kN + i) * kDIM + h * kHD + lane * 2;
    orow[0] = (bf16)o0;
    orow[1] = (bf16)o1;
  }
}

extern "C" void kernel_launch(void* const* d_in, const int* in_sizes, int n_in,
                              void* d_out, int out_size, void* d_ws, size_t ws_size,
                              hipStream_t stream)
{
  // indices of the 22 float tensors in setup_inputs order (skip t,h,w scalars)
  const int map[22] = {0,4,5,6,7,8,9,10,11,12,13,14,15,16,17,18,19,20,21,22,23,24};

  char* ws = (char*)d_ws;
  unsigned* flag = (unsigned*)ws;

  size_t off = 256;
  auto take = [&](size_t bytes) {
    size_t r = off;
    off += (bytes + 255) & ~(size_t)255;
    return r;
  };

  SegTab tab;
  long total = 0;
  tab.start[0] = 0;
  for (int j = 0; j < 22; ++j) {
    tab.src[j] = d_in[map[j]];
    total += in_sizes[map[j]];
    tab.start[j + 1] = total;
  }

  bf16* cin = (bf16*)(ws + take((size_t)total * 2));

  bf16* cp[22];
  { long acc = 0;
    for (int j = 0; j < 22; ++j) { cp[j] = cin + acc; acc += in_sizes[map[j]]; } }
  bf16* x_c    = cp[0];
  bf16* n1g_c  = cp[1],  *n1b_c = cp[2];
  bf16* qkvw_c = cp[3],  *qkvb_c = cp[4];
  bf16* cwq_c  = cp[5],  *nqg_c = cp[6],  *nqb_c = cp[7];
  bf16* cwk_c  = cp[8],  *nkg_c = cp[9],  *nkb_c = cp[10];
  bf16* cwv_c  = cp[11], *nvg_c = cp[12], *nvb_c = cp[13];
  bf16* projw_c = cp[14], *projb_c = cp[15];
  bf16* n2g_c  = cp[16], *n2b_c = cp[17];
  bf16* fc1w_c = cp[18], *fc1b_c = cp[19];
  bf16* fc2w_c = cp[20], *fc2b_c = cp[21];

  bf16* qkv  = (bf16*)(ws + take(38584320));  // also h1 (M x 3072)
  bf16* xn   = (bf16*)(ws + take(9646080));   // also o
  bf16* pool = (bf16*)(ws + take(28938240));  // also x2n
  bf16* x1   = (bf16*)(ws + take(9646080));
  bf16* o   = xn;
  bf16* h1  = qkv;
  bf16* x2n = pool;

  bf16*  out_b = (bf16*)d_out;
  float* out_f = (float*)d_out;

  detect_kernel<<<1, 1, 0, stream>>>((const unsigned*)d_in[4], flag);
  convert_kernel<<<2048, 256, 0, stream>>>(tab, cin, flag, total / 8);

  ln768_kernel<<<kM, 256, 0, stream>>>(x_c, n1g_c, n1b_c, xn);
  gemm_bt<0,0><<<dim3(50, 18), 256, 0, stream>>>(xn, qkvw_c, qkvb_c, nullptr, qkv, nullptr, nullptr, kM, 768, 2304);
  convpool2_kernel<<<dim3(kT, kBNH, 9), 256, 0, stream>>>(qkv, cwq_c, cwk_c, cwv_c, pool);
  ln96_kernel<<<dim3((int)((kPoolRows + 3) / 4), 3), 256, 0, stream>>>(pool, nqg_c, nqb_c, nkg_c, nkb_c, nvg_c, nvb_c);
  attn_kernel<<<(int)((kPoolRows + 3) / 4), 256, 0, stream>>>(pool, o);
  gemm_bt<2,0><<<dim3(50, 6), 256, 0, stream>>>(o, projw_c, projb_c, x_c, x1, nullptr, nullptr, kM, 768, 768);
  ln768_kernel<<<kM, 256, 0, stream>>>(x1, n2g_c, n2b_c, x2n);
  gemm_bt<1,0><<<dim3(50, 24), 256, 0, stream>>>(x2n, fc1w_c, fc1b_c, nullptr, h1, nullptr, nullptr, kM, 768, 3072);
  gemm_bt<2,1><<<dim3(50, 6), 256, 0, stream>>>(h1, fc2w_c, fc2b_c, x1, out_b, out_f, flag, kM, 3072, 768);
}

// Round 4
// 345.436 us; speedup vs baseline: 2.3233x; 1.0137x over previous
//
#include <hip/hip_runtime.h>
#include <hip/hip_bf16.h>
#include <cmath>

using bf16 = __hip_bfloat16;
using bf16x8_t = __attribute__((ext_vector_type(8))) short;
using f32x4_t  = __attribute__((ext_vector_type(4))) float;

constexpr int kT = 8;
constexpr int kDIM = 768, kNH = 8, kHD = 96;
constexpr int kN = 1570;                        // 8*14*14 + 1 + 1
constexpr int kB = 4;
constexpr int kM = kB * kN;                     // 6280
constexpr int kBNH = kB * kNH;                  // 32
constexpr long kPoolRows  = (long)kBNH * kN;    // 50240
constexpr long kPoolElems = kPoolRows * kHD;    // 4,823,040

// ---------------- dtype probe + input conversion ----------------------------
struct SegTab { const void* src[22]; long start[23]; };

__global__ void detect_kernel(const unsigned* __restrict__ probe,
                              unsigned* __restrict__ flag) {
  // norm1_g is all-ones: bf16-pair word = 0x3F803F80, fp32 word = 0x3F800000
  *flag = (probe[0] == 0x3F803F80u) ? 1u : 0u;
}

__global__ void convert_kernel(SegTab tab, bf16* __restrict__ cin,
                               const unsigned* __restrict__ flag, long chunks) {
  const bool isb = (*flag != 0u);
  const long stride = (long)gridDim.x * blockDim.x;
  for (long c = (long)blockIdx.x * blockDim.x + threadIdx.x; c < chunks; c += stride) {
    const long e8 = c * 8;
    int lo = 0, hi = 22;
    while (hi - lo > 1) { int mid = (lo + hi) >> 1; if (e8 >= tab.start[mid]) lo = mid; else hi = mid; }
    const long e = e8 - tab.start[lo];
    if (isb) {
      *(bf16x8_t*)(cin + e8) = *(const bf16x8_t*)((const unsigned short*)tab.src[lo] + e);
    } else {
      const float* s = (const float*)tab.src[lo] + e;
      float4 a = *(const float4*)s;
      float4 b = *(const float4*)(s + 4);
      bf16 r[8];
      r[0] = (bf16)a.x; r[1] = (bf16)a.y; r[2] = (bf16)a.z; r[3] = (bf16)a.w;
      r[4] = (bf16)b.x; r[5] = (bf16)b.y; r[6] = (bf16)b.z; r[7] = (bf16)b.w;
      *(bf16x8_t*)(cin + e8) = *(bf16x8_t*)r;
    }
  }
}

__device__ __forceinline__ void gload_lds16(const bf16* g, bf16* l) {
  __builtin_amdgcn_global_load_lds(
      (const __attribute__((address_space(1))) unsigned int*)g,
      (__attribute__((address_space(3))) unsigned int*)l, 16, 0, 0);
}

// ---------------- GEMM v3: 2-phase dbuf + XCD swizzle + LDS XOR swizzle -----
// C[M,Nout] = A[M,K] @ W[Nout,K]^T + bias. 128x128 tile, BK=32.
// EPI 0: +bias ; EPI 1: +bias then exact GELU ; EPI 2: +bias + residual
// LDS layout: slot(r,c_st) at elems (r*4+c_st)*8 holds global k-chunk
// j = c_st ^ ((r>>1)&3)  -> ds_read phase-conflict-free; dest stays linear
// for global_load_lds (source address carries the swizzle, rule #21).
template<int EPI, int DUAL>
__launch_bounds__(256, 2)
__global__ void gemm_bt(const bf16* __restrict__ A, const bf16* __restrict__ Wt,
                        const bf16* __restrict__ bias, const bf16* __restrict__ res,
                        bf16* __restrict__ C, float* __restrict__ Cf,
                        const unsigned* __restrict__ flagp,
                        int M, int K, int Nout, int tiles_n)
{
  __shared__ bf16 As[2][128 * 32];
  __shared__ bf16 Bs[2][128 * 32];
  const int tid  = threadIdx.x;
  const int lane = tid & 63;
  const int wv   = tid >> 6;
  const int wr   = wv >> 1, wc = wv & 1;

  // bijective XCD swizzle: bids with equal (bid&7) land on one XCD and get a
  // contiguous run of n-fastest tile indices -> A-panel reuse hits same-XCD L2
  const int nwg = gridDim.x;
  const int q = nwg >> 3, rr = nwg & 7;
  const int xcd = blockIdx.x & 7, slot = blockIdx.x >> 3;
  const int base = (xcd < rr) ? xcd * (q + 1) : rr * (q + 1) + (xcd - rr) * q;
  const int lin = base + slot;
  const long tile_m = (long)(lin / tiles_n) * 128;
  const long tile_n = (long)(lin % tiles_n) * 128;

  bool isb = true;
  if constexpr (DUAL) isb = (*flagp != 0u);

  f32x4_t zero = {0.f, 0.f, 0.f, 0.f};
  f32x4_t acc[4][4];
#pragma unroll
  for (int i = 0; i < 4; ++i)
#pragma unroll
    for (int j = 0; j < 4; ++j) acc[i][j] = zero;

  // staging: thread tid covers slots tid (rows 0..63) and tid+256 (rows 64..127)
  const int r0 = tid >> 2;              // 0..63
  const int c0 = tid & 3;
  const int j0 = c0 ^ ((r0 >> 1) & 3);  // same for r0+64 (64/2 % 4 == 0)
  long ar0 = tile_m + r0;      if (ar0 > M - 1) ar0 = M - 1;
  long ar1 = tile_m + r0 + 64; if (ar1 > M - 1) ar1 = M - 1;
  const bf16* Ag0 = A  + ar0 * K + j0 * 8;
  const bf16* Ag1 = A  + ar1 * K + j0 * 8;
  const bf16* Bg0 = Wt + (tile_n + r0) * K + j0 * 8;
  const bf16* Bg1 = Wt + (tile_n + r0 + 64) * K + j0 * 8;

  const int rA = wr * 64 + (lane & 15);
  const int rB = wc * 64 + (lane & 15);
  const int xorv8 = (((lane >> 4) ^ (((lane & 15) >> 1) & 3))) * 8;

  const int ksteps = K >> 5;
  // prologue: stage tile 0 into buffer 0
  gload_lds16(Ag0, &As[0][wv * 512]);
  gload_lds16(Ag1, &As[0][2048 + wv * 512]);
  gload_lds16(Bg0, &Bs[0][wv * 512]);
  gload_lds16(Bg1, &Bs[0][2048 + wv * 512]);
  __syncthreads();

  int cur = 0;
  for (int kt = 0; kt < ksteps; ++kt) {
    if (kt + 1 < ksteps) {             // issue next-tile loads BEFORE compute
      const int k1 = (kt + 1) << 5;
      gload_lds16(Ag0 + k1, &As[cur ^ 1][wv * 512]);
      gload_lds16(Ag1 + k1, &As[cur ^ 1][2048 + wv * 512]);
      gload_lds16(Bg0 + k1, &Bs[cur ^ 1][wv * 512]);
      gload_lds16(Bg1 + k1, &Bs[cur ^ 1][2048 + wv * 512]);
    }
    bf16x8_t a[4], b[4];
#pragma unroll
    for (int m = 0; m < 4; ++m)
      a[m] = *(const bf16x8_t*)&As[cur][(rA + m * 16) * 32 + xorv8];
#pragma unroll
    for (int n = 0; n < 4; ++n)
      b[n] = *(const bf16x8_t*)&Bs[cur][(rB + n * 16) * 32 + xorv8];
#pragma unroll
    for (int m = 0; m < 4; ++m)
#pragma unroll
      for (int n = 0; n < 4; ++n)
        acc[m][n] = __builtin_amdgcn_mfma_f32_16x16x32_bf16(a[m], b[n], acc[m][n], 0, 0, 0);
    __syncthreads();                   // drains stage loads + LDS reads
    cur ^= 1;
  }

  const long colBase = tile_n + wc * 64 + (lane & 15);
  const long rowBase = tile_m + wr * 64 + ((lane >> 4) << 2);
#pragma unroll
  for (int n = 0; n < 4; ++n) {
    const long col = colBase + n * 16;
    const float bv = (float)bias[col];
#pragma unroll
    for (int m = 0; m < 4; ++m) {
      const long row0 = rowBase + m * 16;
#pragma unroll
      for (int r = 0; r < 4; ++r) {
        const long row = row0 + r;
        if (row < M) {
          float v2 = acc[m][n][r] + bv;
          if constexpr (EPI == 1) {
            v2 = 0.5f * v2 * (1.f + erff(v2 * 0.70710678118654752f));
          } else if constexpr (EPI == 2) {
            v2 += (float)res[row * Nout + col];
          }
          if constexpr (DUAL) {
            if (isb) C[row * Nout + col] = (bf16)v2;
            else     Cf[row * Nout + col] = v2;
          } else {
            C[row * Nout + col] = (bf16)v2;
          }
        }
      }
    }
  }
}

// ---------------- LayerNorm over DIM=768, one block per row -----------------
__global__ void ln768_kernel(const bf16* __restrict__ x, const bf16* __restrict__ g,
                             const bf16* __restrict__ bta, bf16* __restrict__ y)
{
  const long row = blockIdx.x;
  const int tid = threadIdx.x;
  const bf16* xr = x + row * kDIM;
  float v[3];
  float s = 0.f, ss = 0.f;
#pragma unroll
  for (int i = 0; i < 3; ++i) {
    v[i] = (float)xr[tid + i * 256];
    s += v[i]; ss += v[i] * v[i];
  }
#pragma unroll
  for (int off = 32; off; off >>= 1) {
    s  += __shfl_xor(s, off);
    ss += __shfl_xor(ss, off);
  }
  __shared__ float red[8];
  const int wv = tid >> 6;
  if ((tid & 63) == 0) { red[wv] = s; red[4 + wv] = ss; }
  __syncthreads();
  s  = red[0] + red[1] + red[2] + red[3];
  ss = red[4] + red[5] + red[6] + red[7];
  const float mean = s * (1.f / kDIM);
  const float var  = ss * (1.f / kDIM) - mean * mean;
  const float rstd = rsqrtf(var + 1e-5f);
  bf16* yr = y + row * kDIM;
#pragma unroll
  for (int i = 0; i < 3; ++i) {
    const int c = tid + i * 256;
    yr[c] = (bf16)((v[i] - mean) * rstd * (float)g[c] + (float)bta[c]);
  }
}

// ---------------- depthwise 3x3x3 conv pooling, LDS-staged v2 ---------------
__launch_bounds__(256, 2)
__global__ void convpool2_kernel(const bf16* __restrict__ qkv,
                                 const bf16* __restrict__ cwq,
                                 const bf16* __restrict__ cwk,
                                 const bf16* __restrict__ cwv,
                                 bf16* __restrict__ pool)
{
  __shared__ bf16 tile[3 * 256 * 40];   // 61,440 B
  const int t    = blockIdx.x;
  const int bh   = blockIdx.y;
  const int z    = blockIdx.z;
  const int s    = z / 3, cgrp = z - s * 3;
  const int tid  = threadIdx.x;
  const int b    = bh >> 3, h = bh & 7;

  const bf16* src0 = qkv + (long)(b * kN) * 2304 + s * kDIM + h * kHD + cgrp * 32;

  {
    f32x4_t z4 = {0.f, 0.f, 0.f, 0.f};
    for (int i = tid; i < 3840; i += 256)
      *(f32x4_t*)((char*)tile + (long)i * 16) = z4;
  }
  __syncthreads();

  for (int c = tid; c < 2352; c += 256) {
    const int slice = c / 784;
    const int rem   = c - slice * 784;
    const int p     = rem >> 2;
    const int seg   = rem & 3;
    const int tt    = t + slice - 1;
    if ((unsigned)tt < 8u) {
      const int y = p / 14, x = p - y * 14;
      const int n = 2 + tt * 196 + p;
      const bf16x8_t v = *(const bf16x8_t*)(src0 + (long)n * 2304 + seg * 8);
      *(bf16x8_t*)((char*)tile + ((long)(slice * 256 + (y + 1) * 16 + (x + 1)) * 40 + seg * 8) * 2) = v;
    }
  }

  const int dpair = tid & 15;
  const int pg    = tid >> 4;
  const int d0    = cgrp * 32 + dpair * 2;
  const bf16* cw  = (s == 0) ? cwq : (s == 1) ? cwk : cwv;
  float w0[27], w1[27];
#pragma unroll
  for (int i = 0; i < 27; ++i) {
    w0[i] = (float)cw[d0 * 27 + i];
    w1[i] = (float)cw[(d0 + 1) * 27 + i];
  }
  __syncthreads();

  bf16* out0 = pool + (long)s * kPoolElems + (long)bh * kN * kHD;
  for (int p = pg; p < 196; p += 16) {
    const int y = p / 14, x = p - y * 14;
    const char* bp = (const char*)tile + ((long)(y * 16 + x) * 40 + dpair * 2) * 2;
    float a0 = 0.f, a1 = 0.f;
#pragma unroll
    for (int dt = 0; dt < 3; ++dt)
#pragma unroll
      for (int dy = 0; dy < 3; ++dy)
#pragma unroll
        for (int dx = 0; dx < 3; ++dx) {
          const unsigned u = *(const unsigned*)(bp + dt * 20480 + dy * 1280 + dx * 80);
          const int i = (dt * 3 + dy) * 3 + dx;
          a0 = fmaf(__uint_as_float(u << 16), w0[i], a0);
          a1 = fmaf(__uint_as_float(u & 0xffff0000u), w1[i], a1);
        }
    const int n = 2 + t * 196 + p;
    bf16 r0 = (bf16)a0, r1 = (bf16)a1;
    unsigned pk = ((unsigned)*(unsigned short*)&r1 << 16) | *(unsigned short*)&r0;
    *(unsigned*)((char*)(out0 + (long)n * kHD + d0)) = pk;
  }
  if (t == 0 && tid < 64) {
    const int tok = tid >> 5, dd = tid & 31;
    out0[(long)tok * kHD + cgrp * 32 + dd] = src0[(long)tok * 2304 + dd];
  }
}

// ---------------- LayerNorm over HD=96, one wave per row, in place ----------
__global__ void ln96_kernel(bf16* __restrict__ pool,
                            const bf16* __restrict__ gq, const bf16* __restrict__ bq,
                            const bf16* __restrict__ gk, const bf16* __restrict__ bk,
                            const bf16* __restrict__ gv, const bf16* __restrict__ bv)
{
  const int z = blockIdx.y;
  bf16* buf = pool + (long)z * kPoolElems;
  const bf16* g  = (z == 0) ? gq : (z == 1) ? gk : gv;
  const bf16* be = (z == 0) ? bq : (z == 1) ? bk : bv;
  const long row = (long)blockIdx.x * 4 + (threadIdx.x >> 6);
  if (row >= kPoolRows) return;
  const int lane = threadIdx.x & 63;
  bf16* p = buf + row * kHD;
  float a0 = 0.f, a1 = 0.f;
  if (lane < 48) {
    a0 = (float)p[lane * 2];
    a1 = (float)p[lane * 2 + 1];
  }
  float sSum = a0 + a1, sSq = a0 * a0 + a1 * a1;
#pragma unroll
  for (int off = 32; off; off >>= 1) {
    sSum += __shfl_xor(sSum, off);
    sSq  += __shfl_xor(sSq, off);
  }
  const float mean = sSum * (1.f / 96);
  const float var  = sSq * (1.f / 96) - mean * mean;
  const float rstd = rsqrtf(var + 1e-5f);
  if (lane < 48) {
    p[lane * 2]     = (bf16)((a0 - mean) * rstd * (float)g[lane * 2]     + (float)be[lane * 2]);
    p[lane * 2 + 1] = (bf16)((a1 - mean) * rstd * (float)g[lane * 2 + 1] + (float)be[lane * 2 + 1]);
  }
}

// ---------------- sparse masked attention: row i attends to {0, i} ----------
__global__ void attn_kernel(const bf16* __restrict__ pool, bf16* __restrict__ o)
{
  const long idx = (long)blockIdx.x * 4 + (threadIdx.x >> 6);
  if (idx >= kPoolRows) return;
  const int bh = (int)(idx / kN);
  const int i  = (int)(idx - (long)bh * kN);
  const int lane = threadIdx.x & 63;
  const bf16* qrow  = pool + ((long)bh * kN + i) * kHD;
  const bf16* kbase = pool + kPoolElems + (long)bh * kN * kHD;
  const bf16* vbase = pool + 2 * kPoolElems + (long)bh * kN * kHD;
  float q0 = 0, q1 = 0, ki0 = 0, ki1 = 0, k00 = 0, k01 = 0;
  float vi0 = 0, vi1 = 0, v00 = 0, v01 = 0;
  if (lane < 48) {
    const int c = lane * 2;
    q0  = (float)qrow[c];                  q1  = (float)qrow[c + 1];
    ki0 = (float)kbase[(long)i * kHD + c]; ki1 = (float)kbase[(long)i * kHD + c + 1];
    k00 = (float)kbase[c];                 k01 = (float)kbase[c + 1];
    vi0 = (float)vbase[(long)i * kHD + c]; vi1 = (float)vbase[(long)i * kHD + c + 1];
    v00 = (float)vbase[c];                 v01 = (float)vbase[c + 1];
  }
  float ds = q0 * ki0 + q1 * ki1;
  float dg = q0 * k00 + q1 * k01;
#pragma unroll
  for (int off = 32; off; off >>= 1) {
    ds += __shfl_xor(ds, off);
    dg += __shfl_xor(dg, off);
  }
  float o0, o1;
  if (i == 0) { o0 = v00; o1 = v01; }
  else {
    const float scale = 0.10206207261596575f; // 96^-0.5
    const float l0 = dg * scale, li = ds * scale;
    const float mx = fmaxf(l0, li);
    const float e0 = __expf(l0 - mx), ei = __expf(li - mx);
    const float inv = 1.f / (e0 + ei);
    o0 = (e0 * v00 + ei * vi0) * inv;
    o1 = (e0 * v01 + ei * vi1) * inv;
  }
  if (lane < 48) {
    const int b = bh >> 3, h = bh & 7;
    bf16* orow = o + ((long)b * kN + i) * kDIM + h * kHD + lane * 2;
    orow[0] = (bf16)o0;
    orow[1] = (bf16)o1;
  }
}

extern "C" void kernel_launch(void* const* d_in, const int* in_sizes, int n_in,
                              void* d_out, int out_size, void* d_ws, size_t ws_size,
                              hipStream_t stream)
{
  const int map[22] = {0,4,5,6,7,8,9,10,11,12,13,14,15,16,17,18,19,20,21,22,23,24};

  char* ws = (char*)d_ws;
  unsigned* flag = (unsigned*)ws;

  size_t off = 256;
  auto take = [&](size_t bytes) {
    size_t r = off;
    off += (bytes + 255) & ~(size_t)255;
    return r;
  };

  SegTab tab;
  long total = 0;
  tab.start[0] = 0;
  for (int j = 0; j < 22; ++j) {
    tab.src[j] = d_in[map[j]];
    total += in_sizes[map[j]];
    tab.start[j + 1] = total;
  }

  bf16* cin = (bf16*)(ws + take((size_t)total * 2));

  bf16* cp[22];
  { long acc = 0;
    for (int j = 0; j < 22; ++j) { cp[j] = cin + acc; acc += in_sizes[map[j]]; } }
  bf16* x_c    = cp[0];
  bf16* n1g_c  = cp[1],  *n1b_c = cp[2];
  bf16* qkvw_c = cp[3],  *qkvb_c = cp[4];
  bf16* cwq_c  = cp[5],  *nqg_c = cp[6],  *nqb_c = cp[7];
  bf16* cwk_c  = cp[8],  *nkg_c = cp[9],  *nkb_c = cp[10];
  bf16* cwv_c  = cp[11], *nvg_c = cp[12], *nvb_c = cp[13];
  bf16* projw_c = cp[14], *projb_c = cp[15];
  bf16* n2g_c  = cp[16], *n2b_c = cp[17];
  bf16* fc1w_c = cp[18], *fc1b_c = cp[19];
  bf16* fc2w_c = cp[20], *fc2b_c = cp[21];

  bf16* qkv  = (bf16*)(ws + take(38584320));  // also h1 (M x 3072)
  bf16* xn   = (bf16*)(ws + take(9646080));   // also o
  bf16* pool = (bf16*)(ws + take(28938240));  // also x2n
  bf16* x1   = (bf16*)(ws + take(9646080));
  bf16* o   = xn;
  bf16* h1  = qkv;
  bf16* x2n = pool;

  bf16*  out_b = (bf16*)d_out;
  float* out_f = (float*)d_out;

  detect_kernel<<<1, 1, 0, stream>>>((const unsigned*)d_in[4], flag);
  convert_kernel<<<2048, 256, 0, stream>>>(tab, cin, flag, total / 8);

  ln768_kernel<<<kM, 256, 0, stream>>>(x_c, n1g_c, n1b_c, xn);
  gemm_bt<0,0><<<50 * 18, 256, 0, stream>>>(xn, qkvw_c, qkvb_c, nullptr, qkv, nullptr, nullptr, kM, 768, 2304, 18);
  convpool2_kernel<<<dim3(kT, kBNH, 9), 256, 0, stream>>>(qkv, cwq_c, cwk_c, cwv_c, pool);
  ln96_kernel<<<dim3((int)((kPoolRows + 3) / 4), 3), 256, 0, stream>>>(pool, nqg_c, nqb_c, nkg_c, nkb_c, nvg_c, nvb_c);
  attn_kernel<<<(int)((kPoolRows + 3) / 4), 256, 0, stream>>>(pool, o);
  gemm_bt<2,0><<<50 * 6, 256, 0, stream>>>(o, projw_c, projb_c, x_c, x1, nullptr, nullptr, kM, 768, 768, 6);
  ln768_kernel<<<kM, 256, 0, stream>>>(x1, n2g_c, n2b_c, x2n);
  gemm_bt<1,0><<<50 * 24, 256, 0, stream>>>(x2n, fc1w_c, fc1b_c, nullptr, h1, nullptr, nullptr, kM, 768, 3072, 24);
  gemm_bt<2,1><<<50 * 6, 256, 0, stream>>>(h1, fc2w_c, fc2b_c, x1, out_b, out_f, flag, kM, 3072, 768, 6);
}

// Round 5
// 314.947 us; speedup vs baseline: 2.5482x; 1.0968x over previous
//
#include <hip/hip_runtime.h>
#include <hip/hip_bf16.h>
#include <cmath>

using bf16 = __hip_bfloat16;
using bf16x8_t = __attribute__((ext_vector_type(8))) short;
using f32x4_t  = __attribute__((ext_vector_type(4))) float;

constexpr int kT = 8;
constexpr int kDIM = 768, kNH = 8, kHD = 96;
constexpr int kN = 1570;                        // 8*14*14 + 1 + 1
constexpr int kB = 4;
constexpr int kM = kB * kN;                     // 6280
constexpr int kBNH = kB * kNH;                  // 32
constexpr long kPoolRows  = (long)kBNH * kN;    // 50240
constexpr long kPoolElems = kPoolRows * kHD;    // 4,823,040

// ---------------- dtype probe + input conversion ----------------------------
struct SegTab { const void* src[22]; long start[23]; };

__global__ void detect_kernel(const unsigned* __restrict__ probe,
                              unsigned* __restrict__ flag) {
  // norm1_g is all-ones: bf16-pair word = 0x3F803F80, fp32 word = 0x3F800000
  *flag = (probe[0] == 0x3F803F80u) ? 1u : 0u;
}

__global__ void convert_kernel(SegTab tab, bf16* __restrict__ cin,
                               const unsigned* __restrict__ flag, long chunks) {
  const bool isb = (*flag != 0u);
  const long stride = (long)gridDim.x * blockDim.x;
  for (long c = (long)blockIdx.x * blockDim.x + threadIdx.x; c < chunks; c += stride) {
    const long e8 = c * 8;
    int lo = 0, hi = 22;
    while (hi - lo > 1) { int mid = (lo + hi) >> 1; if (e8 >= tab.start[mid]) lo = mid; else hi = mid; }
    const long e = e8 - tab.start[lo];
    if (isb) {
      *(bf16x8_t*)(cin + e8) = *(const bf16x8_t*)((const unsigned short*)tab.src[lo] + e);
    } else {
      const float* s = (const float*)tab.src[lo] + e;
      float4 a = *(const float4*)s;
      float4 b = *(const float4*)(s + 4);
      bf16 r[8];
      r[0] = (bf16)a.x; r[1] = (bf16)a.y; r[2] = (bf16)a.z; r[3] = (bf16)a.w;
      r[4] = (bf16)b.x; r[5] = (bf16)b.y; r[6] = (bf16)b.z; r[7] = (bf16)b.w;
      *(bf16x8_t*)(cin + e8) = *(bf16x8_t*)r;
    }
  }
}

__device__ __forceinline__ void gload_lds16(const bf16* g, bf16* l) {
  __builtin_amdgcn_global_load_lds(
      (const __attribute__((address_space(1))) unsigned int*)g,
      (__attribute__((address_space(3))) unsigned int*)l, 16, 0, 0);
}

// ---------------- GEMM v4: counted-vmcnt pipeline, BK=64, 128x128 tile ------
// C[M,Nout] = A[M,K] @ W[Nout,K]^T + bias. EPI 0:+bias 1:+GELU 2:+residual.
// LDS [128 rows][8 chunks of 8 elems]; chunk slot j holds global chunk
// j^(row&7) (swizzle carried by the GLOBAL source address; LDS dest linear,
// rule #21). Steady-state: 2 tiles in flight, s_waitcnt vmcnt(8) (never 0).
template<int EPI, int DUAL>
__launch_bounds__(256, 2)
__global__ void gemm_bt(const bf16* __restrict__ A, const bf16* __restrict__ Wt,
                        const bf16* __restrict__ bias, const bf16* __restrict__ res,
                        bf16* __restrict__ C, float* __restrict__ Cf,
                        const unsigned* __restrict__ flagp,
                        int M, int K, int Nout, int tiles_n)
{
  __shared__ bf16 As[2][128 * 64];
  __shared__ bf16 Bs[2][128 * 64];
  const int tid  = threadIdx.x;
  const int lane = tid & 63;
  const int wv   = tid >> 6;
  const int wr   = wv >> 1, wc = wv & 1;

  // bijective XCD swizzle (n-fastest tile order; A-panel reuse in same-XCD L2)
  const int nwg = gridDim.x;
  const int q = nwg >> 3, rr = nwg & 7;
  const int xcd = blockIdx.x & 7, slot = blockIdx.x >> 3;
  const int base = (xcd < rr) ? xcd * (q + 1) : rr * (q + 1) + (xcd - rr) * q;
  const int lin = base + slot;
  const long tile_m = (long)(lin / tiles_n) * 128;
  const long tile_n = (long)(lin % tiles_n) * 128;

  bool isb = true;
  if constexpr (DUAL) isb = (*flagp != 0u);

  f32x4_t zero = {0.f, 0.f, 0.f, 0.f};
  f32x4_t acc[4][4];
#pragma unroll
  for (int i = 0; i < 4; ++i)
#pragma unroll
    for (int j = 0; j < 4; ++j) acc[i][j] = zero;

  // staging addresses: issue i covers rows i*32 + (tid>>3), chunk slot tid&7
  const int rbase = tid >> 3;
  const int g8 = (((tid & 7) ^ (rbase & 7))) * 8;   // swizzled global chunk
  const bf16* srcA[4];
  const bf16* srcB[4];
#pragma unroll
  for (int i = 0; i < 4; ++i) {
    long ar = tile_m + i * 32 + rbase; if (ar > M - 1) ar = M - 1;
    srcA[i] = A  + ar * K + g8;
    srcB[i] = Wt + (tile_n + i * 32 + rbase) * K + g8;
  }

  // ds_read addressing: logical chunk c of row r lives at slot c^(r&7)
  const int rsel = lane & 15;
  const int qq = lane & 7;
  const int j0 = (((lane >> 4) ^ qq)) * 8;
  const int j1 = (((lane >> 4) ^ 4 ^ qq)) * 8;
  const int rowA0 = wr * 64 + rsel;
  const int rowB0 = wc * 64 + rsel;

  auto stage = [&](int kt, int buf) {
    const long koff = (long)kt << 6;
#pragma unroll
    for (int i = 0; i < 4; ++i)
      gload_lds16(srcA[i] + koff, &As[buf][i * 2048 + wv * 512]);
#pragma unroll
    for (int i = 0; i < 4; ++i)
      gload_lds16(srcB[i] + koff, &Bs[buf][i * 2048 + wv * 512]);
  };

  const int ksteps = K >> 6;
  stage(0, 0);
  stage(1, 1);
  asm volatile("s_waitcnt vmcnt(8)" ::: "memory");   // tile 0 landed
  __builtin_amdgcn_s_barrier();

  int cur = 0;
  for (int kt = 0; kt < ksteps; ++kt) {
    bf16x8_t a[4][2], b[4][2];
#pragma unroll
    for (int m = 0; m < 4; ++m) {
      const int ra = (rowA0 + m * 16) << 6;
      a[m][0] = *(const bf16x8_t*)&As[cur][ra + j0];
      a[m][1] = *(const bf16x8_t*)&As[cur][ra + j1];
      const int rb = (rowB0 + m * 16) << 6;
      b[m][0] = *(const bf16x8_t*)&Bs[cur][rb + j0];
      b[m][1] = *(const bf16x8_t*)&Bs[cur][rb + j1];
    }
    asm volatile("s_waitcnt lgkmcnt(0)" ::: "memory"); // frags in regs
    __builtin_amdgcn_sched_barrier(0);
    __builtin_amdgcn_s_barrier();                      // buf[cur] free
    const bool pf = (kt + 2 < ksteps);
    if (pf) stage(kt + 2, cur);                        // overwrite freed buf
#pragma unroll
    for (int m = 0; m < 4; ++m)
#pragma unroll
      for (int n = 0; n < 4; ++n) {
        acc[m][n] = __builtin_amdgcn_mfma_f32_16x16x32_bf16(a[m][0], b[n][0], acc[m][n], 0, 0, 0);
        acc[m][n] = __builtin_amdgcn_mfma_f32_16x16x32_bf16(a[m][1], b[n][1], acc[m][n], 0, 0, 0);
      }
    if (pf) asm volatile("s_waitcnt vmcnt(8)" ::: "memory"); // t+1 landed, t+2 in flight
    else    asm volatile("s_waitcnt vmcnt(0)" ::: "memory"); // tail drain
    __builtin_amdgcn_s_barrier();
    cur ^= 1;
  }

  const long colBase = tile_n + wc * 64 + (lane & 15);
  const long rowBase = tile_m + wr * 64 + ((lane >> 4) << 2);
#pragma unroll
  for (int n = 0; n < 4; ++n) {
    const long col = colBase + n * 16;
    const float bv = (float)bias[col];
#pragma unroll
    for (int m = 0; m < 4; ++m) {
      const long row0 = rowBase + m * 16;
#pragma unroll
      for (int r = 0; r < 4; ++r) {
        const long row = row0 + r;
        if (row < M) {
          float v2 = acc[m][n][r] + bv;
          if constexpr (EPI == 1) {
            v2 = 0.5f * v2 * (1.f + erff(v2 * 0.70710678118654752f));
          } else if constexpr (EPI == 2) {
            v2 += (float)res[row * Nout + col];
          }
          if constexpr (DUAL) {
            if (isb) C[row * Nout + col] = (bf16)v2;
            else     Cf[row * Nout + col] = v2;
          } else {
            C[row * Nout + col] = (bf16)v2;
          }
        }
      }
    }
  }
}

// ---------------- LayerNorm over DIM=768, one block per row -----------------
__global__ void ln768_kernel(const bf16* __restrict__ x, const bf16* __restrict__ g,
                             const bf16* __restrict__ bta, bf16* __restrict__ y)
{
  const long row = blockIdx.x;
  const int tid = threadIdx.x;
  const bf16* xr = x + row * kDIM;
  float v[3];
  float s = 0.f, ss = 0.f;
#pragma unroll
  for (int i = 0; i < 3; ++i) {
    v[i] = (float)xr[tid + i * 256];
    s += v[i]; ss += v[i] * v[i];
  }
#pragma unroll
  for (int off = 32; off; off >>= 1) {
    s  += __shfl_xor(s, off);
    ss += __shfl_xor(ss, off);
  }
  __shared__ float red[8];
  const int wv = tid >> 6;
  if ((tid & 63) == 0) { red[wv] = s; red[4 + wv] = ss; }
  __syncthreads();
  s  = red[0] + red[1] + red[2] + red[3];
  ss = red[4] + red[5] + red[6] + red[7];
  const float mean = s * (1.f / kDIM);
  const float var  = ss * (1.f / kDIM) - mean * mean;
  const float rstd = rsqrtf(var + 1e-5f);
  bf16* yr = y + row * kDIM;
#pragma unroll
  for (int i = 0; i < 3; ++i) {
    const int c = tid + i * 256;
    yr[c] = (bf16)((v[i] - mean) * rstd * (float)g[c] + (float)bta[c]);
  }
}

// ---------------- depthwise 3x3x3 conv pooling, LDS-staged v2 ---------------
__launch_bounds__(256, 2)
__global__ void convpool2_kernel(const bf16* __restrict__ qkv,
                                 const bf16* __restrict__ cwq,
                                 const bf16* __restrict__ cwk,
                                 const bf16* __restrict__ cwv,
                                 bf16* __restrict__ pool)
{
  __shared__ bf16 tile[3 * 256 * 40];   // 61,440 B
  const int t    = blockIdx.x;
  const int bh   = blockIdx.y;
  const int z    = blockIdx.z;
  const int s    = z / 3, cgrp = z - s * 3;
  const int tid  = threadIdx.x;
  const int b    = bh >> 3, h = bh & 7;

  const bf16* src0 = qkv + (long)(b * kN) * 2304 + s * kDIM + h * kHD + cgrp * 32;

  {
    f32x4_t z4 = {0.f, 0.f, 0.f, 0.f};
    for (int i = tid; i < 3840; i += 256)
      *(f32x4_t*)((char*)tile + (long)i * 16) = z4;
  }
  __syncthreads();

  for (int c = tid; c < 2352; c += 256) {
    const int slice = c / 784;
    const int rem   = c - slice * 784;
    const int p     = rem >> 2;
    const int seg   = rem & 3;
    const int tt    = t + slice - 1;
    if ((unsigned)tt < 8u) {
      const int y = p / 14, x = p - y * 14;
      const int n = 2 + tt * 196 + p;
      const bf16x8_t v = *(const bf16x8_t*)(src0 + (long)n * 2304 + seg * 8);
      *(bf16x8_t*)((char*)tile + ((long)(slice * 256 + (y + 1) * 16 + (x + 1)) * 40 + seg * 8) * 2) = v;
    }
  }

  const int dpair = tid & 15;
  const int pg    = tid >> 4;
  const int d0    = cgrp * 32 + dpair * 2;
  const bf16* cw  = (s == 0) ? cwq : (s == 1) ? cwk : cwv;
  float w0[27], w1[27];
#pragma unroll
  for (int i = 0; i < 27; ++i) {
    w0[i] = (float)cw[d0 * 27 + i];
    w1[i] = (float)cw[(d0 + 1) * 27 + i];
  }
  __syncthreads();

  bf16* out0 = pool + (long)s * kPoolElems + (long)bh * kN * kHD;
  for (int p = pg; p < 196; p += 16) {
    const int y = p / 14, x = p - y * 14;
    const char* bp = (const char*)tile + ((long)(y * 16 + x) * 40 + dpair * 2) * 2;
    float a0 = 0.f, a1 = 0.f;
#pragma unroll
    for (int dt = 0; dt < 3; ++dt)
#pragma unroll
      for (int dy = 0; dy < 3; ++dy)
#pragma unroll
        for (int dx = 0; dx < 3; ++dx) {
          const unsigned u = *(const unsigned*)(bp + dt * 20480 + dy * 1280 + dx * 80);
          const int i = (dt * 3 + dy) * 3 + dx;
          a0 = fmaf(__uint_as_float(u << 16), w0[i], a0);
          a1 = fmaf(__uint_as_float(u & 0xffff0000u), w1[i], a1);
        }
    const int n = 2 + t * 196 + p;
    bf16 r0 = (bf16)a0, r1 = (bf16)a1;
    unsigned pk = ((unsigned)*(unsigned short*)&r1 << 16) | *(unsigned short*)&r0;
    *(unsigned*)((char*)(out0 + (long)n * kHD + d0)) = pk;
  }
  if (t == 0 && tid < 64) {
    const int tok = tid >> 5, dd = tid & 31;
    out0[(long)tok * kHD + cgrp * 32 + dd] = src0[(long)tok * 2304 + dd];
  }
}

// ---------------- LayerNorm over HD=96, one wave per row, in place ----------
__global__ void ln96_kernel(bf16* __restrict__ pool,
                            const bf16* __restrict__ gq, const bf16* __restrict__ bq,
                            const bf16* __restrict__ gk, const bf16* __restrict__ bk,
                            const bf16* __restrict__ gv, const bf16* __restrict__ bv)
{
  const int z = blockIdx.y;
  bf16* buf = pool + (long)z * kPoolElems;
  const bf16* g  = (z == 0) ? gq : (z == 1) ? gk : gv;
  const bf16* be = (z == 0) ? bq : (z == 1) ? bk : bv;
  const long row = (long)blockIdx.x * 4 + (threadIdx.x >> 6);
  if (row >= kPoolRows) return;
  const int lane = threadIdx.x & 63;
  bf16* p = buf + row * kHD;
  float a0 = 0.f, a1 = 0.f;
  if (lane < 48) {
    a0 = (float)p[lane * 2];
    a1 = (float)p[lane * 2 + 1];
  }
  float sSum = a0 + a1, sSq = a0 * a0 + a1 * a1;
#pragma unroll
  for (int off = 32; off; off >>= 1) {
    sSum += __shfl_xor(sSum, off);
    sSq  += __shfl_xor(sSq, off);
  }
  const float mean = sSum * (1.f / 96);
  const float var  = sSq * (1.f / 96) - mean * mean;
  const float rstd = rsqrtf(var + 1e-5f);
  if (lane < 48) {
    p[lane * 2]     = (bf16)((a0 - mean) * rstd * (float)g[lane * 2]     + (float)be[lane * 2]);
    p[lane * 2 + 1] = (bf16)((a1 - mean) * rstd * (float)g[lane * 2 + 1] + (float)be[lane * 2 + 1]);
  }
}

// ---------------- sparse masked attention: row i attends to {0, i} ----------
__global__ void attn_kernel(const bf16* __restrict__ pool, bf16* __restrict__ o)
{
  const long idx = (long)blockIdx.x * 4 + (threadIdx.x >> 6);
  if (idx >= kPoolRows) return;
  const int bh = (int)(idx / kN);
  const int i  = (int)(idx - (long)bh * kN);
  const int lane = threadIdx.x & 63;
  const bf16* qrow  = pool + ((long)bh * kN + i) * kHD;
  const bf16* kbase = pool + kPoolElems + (long)bh * kN * kHD;
  const bf16* vbase = pool + 2 * kPoolElems + (long)bh * kN * kHD;
  float q0 = 0, q1 = 0, ki0 = 0, ki1 = 0, k00 = 0, k01 = 0;
  float vi0 = 0, vi1 = 0, v00 = 0, v01 = 0;
  if (lane < 48) {
    const int c = lane * 2;
    q0  = (float)qrow[c];                  q1  = (float)qrow[c + 1];
    ki0 = (float)kbase[(long)i * kHD + c]; ki1 = (float)kbase[(long)i * kHD + c + 1];
    k00 = (float)kbase[c];                 k01 = (float)kbase[c + 1];
    vi0 = (float)vbase[(long)i * kHD + c]; vi1 = (float)vbase[(long)i * kHD + c + 1];
    v00 = (float)vbase[c];                 v01 = (float)vbase[c + 1];
  }
  float ds = q0 * ki0 + q1 * ki1;
  float dg = q0 * k00 + q1 * k01;
#pragma unroll
  for (int off = 32; off; off >>= 1) {
    ds += __shfl_xor(ds, off);
    dg += __shfl_xor(dg, off);
  }
  float o0, o1;
  if (i == 0) { o0 = v00; o1 = v01; }
  else {
    const float scale = 0.10206207261596575f; // 96^-0.5
    const float l0 = dg * scale, li = ds * scale;
    const float mx = fmaxf(l0, li);
    const float e0 = __expf(l0 - mx), ei = __expf(li - mx);
    const float inv = 1.f / (e0 + ei);
    o0 = (e0 * v00 + ei * vi0) * inv;
    o1 = (e0 * v01 + ei * vi1) * inv;
  }
  if (lane < 48) {
    const int b = bh >> 3, h = bh & 7;
    bf16* orow = o + ((long)b * kN + i) * kDIM + h * kHD + lane * 2;
    orow[0] = (bf16)o0;
    orow[1] = (bf16)o1;
  }
}

extern "C" void kernel_launch(void* const* d_in, const int* in_sizes, int n_in,
                              void* d_out, int out_size, void* d_ws, size_t ws_size,
                              hipStream_t stream)
{
  const int map[22] = {0,4,5,6,7,8,9,10,11,12,13,14,15,16,17,18,19,20,21,22,23,24};

  char* ws = (char*)d_ws;
  unsigned* flag = (unsigned*)ws;

  size_t off = 256;
  auto take = [&](size_t bytes) {
    size_t r = off;
    off += (bytes + 255) & ~(size_t)255;
    return r;
  };

  SegTab tab;
  long total = 0;
  tab.start[0] = 0;
  for (int j = 0; j < 22; ++j) {
    tab.src[j] = d_in[map[j]];
    total += in_sizes[map[j]];
    tab.start[j + 1] = total;
  }

  bf16* cin = (bf16*)(ws + take((size_t)total * 2));

  bf16* cp[22];
  { long acc = 0;
    for (int j = 0; j < 22; ++j) { cp[j] = cin + acc; acc += in_sizes[map[j]]; } }
  bf16* x_c    = cp[0];
  bf16* n1g_c  = cp[1],  *n1b_c = cp[2];
  bf16* qkvw_c = cp[3],  *qkvb_c = cp[4];
  bf16* cwq_c  = cp[5],  *nqg_c = cp[6],  *nqb_c = cp[7];
  bf16* cwk_c  = cp[8],  *nkg_c = cp[9],  *nkb_c = cp[10];
  bf16* cwv_c  = cp[11], *nvg_c = cp[12], *nvb_c = cp[13];
  bf16* projw_c = cp[14], *projb_c = cp[15];
  bf16* n2g_c  = cp[16], *n2b_c = cp[17];
  bf16* fc1w_c = cp[18], *fc1b_c = cp[19];
  bf16* fc2w_c = cp[20], *fc2b_c = cp[21];

  bf16* qkv  = (bf16*)(ws + take(38584320));  // also h1 (M x 3072)
  bf16* xn   = (bf16*)(ws + take(9646080));   // also o
  bf16* pool = (bf16*)(ws + take(28938240));  // also x2n
  bf16* x1   = (bf16*)(ws + take(9646080));
  bf16* o   = xn;
  bf16* h1  = qkv;
  bf16* x2n = pool;

  bf16*  out_b = (bf16*)d_out;
  float* out_f = (float*)d_out;

  detect_kernel<<<1, 1, 0, stream>>>((const unsigned*)d_in[4], flag);
  convert_kernel<<<2048, 256, 0, stream>>>(tab, cin, flag, total / 8);

  ln768_kernel<<<kM, 256, 0, stream>>>(x_c, n1g_c, n1b_c, xn);
  gemm_bt<0,0><<<50 * 18, 256, 0, stream>>>(xn, qkvw_c, qkvb_c, nullptr, qkv, nullptr, nullptr, kM, 768, 2304, 18);
  convpool2_kernel<<<dim3(kT, kBNH, 9), 256, 0, stream>>>(qkv, cwq_c, cwk_c, cwv_c, pool);
  ln96_kernel<<<dim3((int)((kPoolRows + 3) / 4), 3), 256, 0, stream>>>(pool, nqg_c, nqb_c, nkg_c, nkb_c, nvg_c, nvb_c);
  attn_kernel<<<(int)((kPoolRows + 3) / 4), 256, 0, stream>>>(pool, o);
  gemm_bt<2,0><<<50 * 6, 256, 0, stream>>>(o, projw_c, projb_c, x_c, x1, nullptr, nullptr, kM, 768, 768, 6);
  ln768_kernel<<<kM, 256, 0, stream>>>(x1, n2g_c, n2b_c, x2n);
  gemm_bt<1,0><<<50 * 24, 256, 0, stream>>>(x2n, fc1w_c, fc1b_c, nullptr, h1, nullptr, nullptr, kM, 768, 3072, 24);
  gemm_bt<2,1><<<50 * 6, 256, 0, stream>>>(h1, fc2w_c, fc2b_c, x1, out_b, out_f, flag, kM, 3072, 768, 6);
}